// Round 9
// baseline (1402.376 us; speedup 1.0000x reference)
//
#include <hip/hip_runtime.h>
#include <hip/hip_bf16.h>
#include <cstdint>

typedef __attribute__((ext_vector_type(8))) short bf16x8;
typedef __attribute__((ext_vector_type(4))) float f32x4;
typedef unsigned short u16;

#define DEV __device__ __forceinline__

DEV float b2f(u16 u) {
  union { unsigned int i; float f; } v; v.i = ((unsigned int)u) << 16; return v.f;
}
DEV u16 f2b(float f) {
  __hip_bfloat16 h = __float2bfloat16(f);
  return *reinterpret_cast<u16*>(&h);
}
DEV float gelu_f(float x) { return 0.5f * x * (1.0f + erff(x * 0.70710678118654752f)); }

DEV void async_cp16(const u16* g, u16* l) {
  __builtin_amdgcn_global_load_lds(
      (const __attribute__((address_space(1))) void*)g,
      (__attribute__((address_space(3))) void*)l, 16, 0, 0);
}

// ---- dtype canonicalization ------------------------------------------------
__global__ void probe_kernel(const unsigned int* __restrict__ g, int* __restrict__ flag) {
  if (threadIdx.x == 0 && blockIdx.x == 0) *flag = (*g == 0x3F800000u) ? 1 : 0;
}

struct CvtArgs {
  const void* src[42];
  unsigned int off[43];
};

struct alignas(16) U8v { u16 u[8]; };

__global__ __launch_bounds__(256) void cvt_kernel(CvtArgs a, int n_t, unsigned int total,
                                                  const int* __restrict__ flag,
                                                  u16* __restrict__ dst) {
  unsigned int i8 = (blockIdx.x * 256u + threadIdx.x) * 8u;
  if (i8 >= total) return;
  int t = 0;
  while (t + 1 < n_t && i8 >= a.off[t + 1]) t++;
  unsigned int j = i8 - a.off[t];
  bool in_seg = (i8 + 8 <= a.off[t + 1]) && (i8 + 8 <= total);
  int fp32 = *flag;
  if (fp32) {
    if (in_seg && ((j & 3) == 0)) {
      const float* s = (const float*)a.src[t] + j;
      float4 v0 = *(const float4*)s;
      float4 v1 = *(const float4*)(s + 4);
      U8v o;
      o.u[0] = f2b(v0.x); o.u[1] = f2b(v0.y); o.u[2] = f2b(v0.z); o.u[3] = f2b(v0.w);
      o.u[4] = f2b(v1.x); o.u[5] = f2b(v1.y); o.u[6] = f2b(v1.z); o.u[7] = f2b(v1.w);
      *(U8v*)(dst + i8) = o;
    } else {
      for (int k = 0; k < 8; k++) {
        unsigned int i = i8 + k;
        if (i >= total) break;
        int tt = t;
        while (tt + 1 < n_t && i >= a.off[tt + 1]) tt++;
        dst[i] = f2b(((const float*)a.src[tt])[i - a.off[tt]]);
      }
    }
  } else {
    if (in_seg && ((j & 7) == 0)) {
      *(U8v*)(dst + i8) = *(const U8v*)((const u16*)a.src[t] + j);
    } else {
      for (int k = 0; k < 8; k++) {
        unsigned int i = i8 + k;
        if (i >= total) break;
        int tt = t;
        while (tt + 1 < n_t && i >= a.off[tt + 1]) tt++;
        dst[i] = ((const u16*)a.src[tt])[i - a.off[tt]];
      }
    }
  }
}

// ---- single-wave barrier-free GEMM, depth-2 prefetch, XOR-swizzled LDS ------
// 1 wave/block, 64x64 tile, 3 LDS buffers (24 KB), s_waitcnt vmcnt(16/8/0).
// Staging swizzle: lane (r=l>>2, c=l&3) loads global col-block c ^ ((r>>1)&3);
// reader XORs the same term -> LDS reads hit all 8 granule groups 2x (free).
DEV void stage32(const u16* ga, const u16* gb, int K, int kt, u16* buf, int l) {
#pragma unroll
  for (int j = 0; j < 4; j++) {
    async_cp16(ga + (size_t)(16 * j) * K + kt, buf + j * 512 + l * 8);
    async_cp16(gb + (size_t)(16 * j) * K + kt, buf + 2048 + j * 512 + l * 8);
  }
}

DEV void wave_k_loop(const u16* ga, const u16* gb, int K, int kLen,
                     u16* b0, u16* b1, u16* b2, int l, f32x4 (&acc)[4][4]) {
  int col = l & 15, quad = l >> 4;
  int sR = (col >> 1) & 3;             // read-side swizzle (same for all mi/ni)
  int q8 = (quad ^ sR) * 8;
  int nK = kLen >> 5;
  u16* bufs[3] = {b0, b1, b2};
  stage32(ga, gb, K, 0, b0, l);
  if (nK > 1) stage32(ga, gb, K, 32, b1, l);
  int ib = 0, is = 2;
  for (int ki = 0; ki < nK; ki++) {
    u16* cur = bufs[ib];
    if (ki + 2 < nK) {
      stage32(ga, gb, K, (ki + 2) << 5, bufs[is], l);
      __builtin_amdgcn_s_waitcnt(0x4F70);  // vmcnt(16): current tile landed
    } else if (ki + 1 < nK) {
      __builtin_amdgcn_s_waitcnt(0x0F78);  // vmcnt(8)
    } else {
      __builtin_amdgcn_s_waitcnt(0x0F70);  // vmcnt(0)
    }
    __builtin_amdgcn_sched_barrier(0);     // keep ds_reads below the wait
    bf16x8 af[4], bfv[4];
#pragma unroll
    for (int mi = 0; mi < 4; mi++)
      af[mi] = *(const bf16x8*)&cur[(mi * 16 + col) * 32 + q8];
#pragma unroll
    for (int ni = 0; ni < 4; ni++)
      bfv[ni] = *(const bf16x8*)&cur[2048 + (ni * 16 + col) * 32 + q8];
#pragma unroll
    for (int mi = 0; mi < 4; mi++)
#pragma unroll
      for (int ni = 0; ni < 4; ni++)
        acc[mi][ni] = __builtin_amdgcn_mfma_f32_16x16x32_bf16(af[mi], bfv[ni], acc[mi][ni], 0, 0, 0);
    if (++ib == 3) ib = 0;
    if (++is == 3) is = 0;
  }
}

// mode 0: bf16 out = x + bias
// mode 1: bf16 out = gelu(x + bias)
// mode 3: f32 atomicAdd(out, x + bias); bias only from blockIdx.z==0
__global__ __launch_bounds__(64) void gemm_w64(
    const u16* __restrict__ A, const u16* __restrict__ W,
    const u16* __restrict__ bias,
    u16* __restrict__ outB, float* __restrict__ outF,
    int N, int K, int kLen, int mode)
{
  __shared__ __align__(16) u16 lds[3][4096];
  int l = threadIdx.x;
  int col = l & 15, quad = l >> 4;
  int m0 = blockIdx.x * 64;
  int n0 = blockIdx.y * 64;
  int k0 = blockIdx.z * kLen;
  int r = l >> 2;
  int gcb = (l & 3) ^ ((r >> 1) & 3);   // store-side swizzle
  const u16* ga = A + (size_t)(m0 + r) * K + k0 + gcb * 8;
  const u16* gb = W + (size_t)(n0 + r) * K + k0 + gcb * 8;

  f32x4 acc[4][4];
#pragma unroll
  for (int i = 0; i < 4; i++)
#pragma unroll
    for (int j = 0; j < 4; j++) acc[i][j] = (f32x4){0.f, 0.f, 0.f, 0.f};

  wave_k_loop(ga, gb, K, kLen, &lds[0][0], &lds[1][0], &lds[2][0], l, acc);

  bool addBias = (mode != 3) || (blockIdx.z == 0);
#pragma unroll
  for (int mi = 0; mi < 4; mi++) {
#pragma unroll
    for (int ni = 0; ni < 4; ni++) {
      int n = n0 + ni * 16 + col;
      float bv = addBias ? b2f(bias[n]) : 0.0f;
      f32x4 v = acc[mi][ni];
#pragma unroll
      for (int rr = 0; rr < 4; rr++) {
        int m = m0 + mi * 16 + quad * 4 + rr;
        float x = v[rr] + bv;
        if (mode == 0) {
          outB[(size_t)m * N + n] = f2b(x);
        } else if (mode == 1) {
          outB[(size_t)m * N + n] = f2b(gelu_f(x));
        } else {
          atomicAdd(&outF[(size_t)m * N + n], x);
        }
      }
    }
  }
}

// Fused Q,K,V: blockIdx.y in [0,24): sel=y>>3 picks {Wq,Wk,Wv}, nb=y&7.
__global__ __launch_bounds__(64) void gemm_qkv_w64(
    const u16* __restrict__ A,
    const u16* __restrict__ Wq, const u16* __restrict__ Wk, const u16* __restrict__ Wv,
    const u16* __restrict__ bq, const u16* __restrict__ bk, const u16* __restrict__ bv,
    u16* __restrict__ outBase, size_t outStride, int K)
{
  __shared__ __align__(16) u16 lds[3][4096];
  int l = threadIdx.x;
  int col = l & 15, quad = l >> 4;
  int m0 = blockIdx.x * 64;
  int sel = blockIdx.y >> 3;
  int n0 = (blockIdx.y & 7) * 64;
  const u16* W = sel == 0 ? Wq : (sel == 1 ? Wk : Wv);
  const u16* bias = sel == 0 ? bq : (sel == 1 ? bk : bv);
  u16* outB = outBase + (size_t)sel * outStride;
  int r = l >> 2;
  int gcb = (l & 3) ^ ((r >> 1) & 3);
  const u16* ga = A + (size_t)(m0 + r) * K + gcb * 8;
  const u16* gb = W + (size_t)(n0 + r) * K + gcb * 8;

  f32x4 acc[4][4];
#pragma unroll
  for (int i = 0; i < 4; i++)
#pragma unroll
    for (int j = 0; j < 4; j++) acc[i][j] = (f32x4){0.f, 0.f, 0.f, 0.f};

  wave_k_loop(ga, gb, K, K, &lds[0][0], &lds[1][0], &lds[2][0], l, acc);

#pragma unroll
  for (int mi = 0; mi < 4; mi++) {
#pragma unroll
    for (int ni = 0; ni < 4; ni++) {
      int n = n0 + ni * 16 + col;
      float bv = b2f(bias[n]);
      f32x4 v = acc[mi][ni];
#pragma unroll
      for (int rr = 0; rr < 4; rr++) {
        int m = m0 + mi * 16 + quad * 4 + rr;
        outB[(size_t)m * 512 + n] = f2b(v[rr] + bv);
      }
    }
  }
}

// z[m][n] = pos[(m&511)*512+n]  (fp32 residual init)
__global__ __launch_bounds__(256) void zinit_kernel(const u16* __restrict__ pos,
                                                    float* __restrict__ z)
{
  int i = (blockIdx.x * 256 + threadIdx.x) * 8;
  int n = i & 511;
  int m = i >> 9;
  int s = m & 511;
  U8v p = *(const U8v*)&pos[s * 512 + n];
  float4 o0 = {b2f(p.u[0]), b2f(p.u[1]), b2f(p.u[2]), b2f(p.u[3])};
  float4 o1 = {b2f(p.u[4]), b2f(p.u[5]), b2f(p.u[6]), b2f(p.u[7])};
  *(float4*)(z + i) = o0;
  *(float4*)(z + i + 4) = o1;
}

// dst[m][ci*3+tap] = src[m+tap-1][ci] (zero-padded along s within each batch)
__global__ void im2col3_kernel(const u16* __restrict__ src,
                               u16* __restrict__ dst, int C)
{
  int m = blockIdx.x;
  int k = blockIdx.y * blockDim.x + threadIdx.x;
  int ci = k / 3;
  int tap = k - ci * 3;
  int s = m & 511;
  int sp = s + tap - 1;
  u16 val = 0;
  if (sp >= 0 && sp < 512) val = src[(size_t)(m + tap - 1) * C + ci];
  dst[(size_t)m * (3 * C) + k] = val;
}

// LayerNorm over D=512; one wave per row; z fp32 -> bf16 out.
__global__ __launch_bounds__(256) void ln_kernel(
    const float* __restrict__ z, const u16* __restrict__ gam,
    const u16* __restrict__ bet, u16* __restrict__ out)
{
  int w = threadIdx.x >> 6, l = threadIdx.x & 63;
  int row = blockIdx.x * 4 + w;
  const float* zr = z + (size_t)row * 512;
  float4 v0 = *(const float4*)(zr + l * 8);
  float4 v1 = *(const float4*)(zr + l * 8 + 4);
  float x[8] = {v0.x, v0.y, v0.z, v0.w, v1.x, v1.y, v1.z, v1.w};
  float s = 0.f;
#pragma unroll
  for (int i = 0; i < 8; i++) s += x[i];
#pragma unroll
  for (int mm = 1; mm < 64; mm <<= 1) s += __shfl_xor(s, mm, 64);
  float mu = s * (1.0f / 512.0f);
  float vs = 0.f;
#pragma unroll
  for (int i = 0; i < 8; i++) { float d = x[i] - mu; vs += d * d; }
#pragma unroll
  for (int mm = 1; mm < 64; mm <<= 1) vs += __shfl_xor(vs, mm, 64);
  float rs = rsqrtf(vs * (1.0f / 512.0f) + 1e-5f);
  U8v gg = *(const U8v*)(gam + l * 8);
  U8v bb = *(const U8v*)(bet + l * 8);
  U8v o;
#pragma unroll
  for (int i = 0; i < 8; i++) o.u[i] = f2b((x[i] - mu) * rs * b2f(gg.u[i]) + b2f(bb.u[i]));
  *(U8v*)(out + (size_t)row * 512 + l * 8) = o;
}

// Final LN on last token only: 16 rows (b, s=511) -> feat[b][512]
__global__ __launch_bounds__(256) void lnf_kernel(
    const float* __restrict__ z, const u16* __restrict__ gam,
    const u16* __restrict__ bet, u16* __restrict__ feat)
{
  int w = threadIdx.x >> 6, l = threadIdx.x & 63;
  int b = blockIdx.x * 4 + w;
  const float* zr = z + ((size_t)b * 512 + 511) * 512;
  float4 v0 = *(const float4*)(zr + l * 8);
  float4 v1 = *(const float4*)(zr + l * 8 + 4);
  float x[8] = {v0.x, v0.y, v0.z, v0.w, v1.x, v1.y, v1.z, v1.w};
  float s = 0.f;
#pragma unroll
  for (int i = 0; i < 8; i++) s += x[i];
#pragma unroll
  for (int mm = 1; mm < 64; mm <<= 1) s += __shfl_xor(s, mm, 64);
  float mu = s * (1.0f / 512.0f);
  float vs = 0.f;
#pragma unroll
  for (int i = 0; i < 8; i++) { float d = x[i] - mu; vs += d * d; }
#pragma unroll
  for (int mm = 1; mm < 64; mm <<= 1) vs += __shfl_xor(vs, mm, 64);
  float rs = rsqrtf(vs * (1.0f / 512.0f) + 1e-5f);
  U8v gg = *(const U8v*)(gam + l * 8);
  U8v bb = *(const U8v*)(bet + l * 8);
  U8v o;
#pragma unroll
  for (int i = 0; i < 8; i++) o.u[i] = f2b((x[i] - mu) * rs * b2f(gg.u[i]) + b2f(bb.u[i]));
  *(U8v*)(feat + (size_t)b * 512 + l * 8) = o;
}

// V (b,s,h*64+e) -> VT (b,h,e,s)
__global__ __launch_bounds__(256) void vtrans_kernel(const u16* __restrict__ V,
                                                     u16* __restrict__ VT)
{
  __shared__ u16 tile[64][72];
  int s0 = blockIdx.x * 64;
  int bh = blockIdx.y; int b = bh >> 3, h = bh & 7;
  int t = threadIdx.x;
  int rs = t >> 2, c = (t & 3) * 16;
  const u16* src = V + ((size_t)(b * 512 + s0 + rs) * 512 + h * 64 + c);
  *(float4*)&tile[rs][c] = *(const float4*)src;
  *(float4*)&tile[rs][c + 8] = *(const float4*)(src + 8);
  __syncthreads();
  u16* dst = VT + ((size_t)(bh * 64 + rs) * 512 + s0 + c);
  union { u16 u[16]; float4 f[2]; } ot;
#pragma unroll
  for (int i = 0; i < 16; i++) ot.u[i] = tile[c + i][rs];
  *(float4*)dst = ot.f[0];
  *(float4*)(dst + 8) = ot.f[1];
}

// Fused masked attention, flash-style. Grid (S/64, B*H).
__global__ __launch_bounds__(256) void attn_kernel(
    const u16* __restrict__ Q, const u16* __restrict__ Kg,
    const u16* __restrict__ VT, u16* __restrict__ O)
{
  __shared__ __align__(16) u16 Qs[64 * 64];
  __shared__ __align__(16) u16 Ks[64 * 64];
  __shared__ __align__(16) u16 Vts[64 * 64];
  __shared__ __align__(16) u16 Ps[64 * 64];
  const float NEG = -1e30f;
  int bh = blockIdx.y; int b = bh >> 3, h = bh & 7;
  int i0 = blockIdx.x * 64;
  int t = threadIdx.x, w = t >> 6, l = t & 63;
  int col = l & 15, quad = l >> 4;
  int dil = 1 << (h < 4 ? h : 4);
  int per_m1 = 2 * dil - 1;

  {
    int row = t >> 2, c = (t & 3) * 16;
    const u16* src = Q + ((size_t)(b * 512 + i0 + row) * 512 + h * 64 + c);
    *(float4*)&Qs[row * 64 + c] = *(const float4*)src;
    *(float4*)&Qs[row * 64 + c + 8] = *(const float4*)(src + 8);
  }
  __syncthreads();

  bf16x8 qa[2];
#pragma unroll
  for (int kk = 0; kk < 2; kk++)
    qa[kk] = *(const bf16x8*)&Qs[(w * 16 + col) * 64 + kk * 32 + quad * 8];

  f32x4 acc_o[4];
#pragma unroll
  for (int i = 0; i < 4; i++) acc_o[i] = (f32x4){0.f, 0.f, 0.f, 0.f};
  float m_run[4], l_run[4];
#pragma unroll
  for (int r = 0; r < 4; r++) { m_run[r] = NEG; l_run[r] = 0.f; }

  for (int jt = 0; jt < 8; jt++) {
    int j0 = jt * 64;
    {
      int row = t >> 2, c = (t & 3) * 16;
      const u16* ks = Kg + ((size_t)(b * 512 + j0 + row) * 512 + h * 64 + c);
      *(float4*)&Ks[row * 64 + c] = *(const float4*)ks;
      *(float4*)&Ks[row * 64 + c + 8] = *(const float4*)(ks + 8);
      const u16* vs = VT + ((size_t)(bh * 64 + row) * 512 + j0 + c);
      *(float4*)&Vts[row * 64 + c] = *(const float4*)vs;
      *(float4*)&Vts[row * 64 + c + 8] = *(const float4*)(vs + 8);
    }
    __syncthreads();

    f32x4 sa[4];
#pragma unroll
    for (int ni = 0; ni < 4; ni++) {
      f32x4 s = (f32x4){0.f, 0.f, 0.f, 0.f};
#pragma unroll
      for (int kk = 0; kk < 2; kk++) {
        bf16x8 kb = *(const bf16x8*)&Ks[(ni * 16 + col) * 64 + kk * 32 + quad * 8];
        s = __builtin_amdgcn_mfma_f32_16x16x32_bf16(qa[kk], kb, s, 0, 0, 0);
      }
      sa[ni] = s;
    }

    float pv[4][4];
    float alpha_r[4];
#pragma unroll
    for (int r = 0; r < 4; r++) {
      int ig = i0 + w * 16 + quad * 4 + r;
      float sv[4]; float mx = NEG;
#pragma unroll
      for (int ni = 0; ni < 4; ni++) {
        int jg = j0 + ni * 16 + col;
        int d = ig - jg; d = d < 0 ? -d : d;
        bool keep = (d <= dil) || ((d & per_m1) == 0);
        float s = keep ? fminf(sa[ni][r] * 0.125f, 80.0f) : NEG;
        sv[ni] = s; mx = fmaxf(mx, s);
      }
#pragma unroll
      for (int mm = 1; mm < 16; mm <<= 1) mx = fmaxf(mx, __shfl_xor(mx, mm, 64));
      float mN = fmaxf(m_run[r], mx);
      float a = __expf(m_run[r] - mN);
      float rsum = 0.f;
#pragma unroll
      for (int ni = 0; ni < 4; ni++) { float p = __expf(sv[ni] - mN); pv[ni][r] = p; rsum += p; }
#pragma unroll
      for (int mm = 1; mm < 16; mm <<= 1) rsum += __shfl_xor(rsum, mm, 64);
      l_run[r] = l_run[r] * a + rsum;
      m_run[r] = mN;
      alpha_r[r] = a;
    }
#pragma unroll
    for (int ne = 0; ne < 4; ne++)
#pragma unroll
      for (int r = 0; r < 4; r++) acc_o[ne][r] *= alpha_r[r];
#pragma unroll
    for (int ni = 0; ni < 4; ni++)
#pragma unroll
      for (int r = 0; r < 4; r++)
        Ps[(w * 16 + quad * 4 + r) * 64 + ni * 16 + col] = f2b(pv[ni][r]);
    __syncthreads();

    bf16x8 pa[2];
#pragma unroll
    for (int kk = 0; kk < 2; kk++)
      pa[kk] = *(const bf16x8*)&Ps[(w * 16 + col) * 64 + kk * 32 + quad * 8];
#pragma unroll
    for (int ne = 0; ne < 4; ne++) {
#pragma unroll
      for (int kk = 0; kk < 2; kk++) {
        bf16x8 vb = *(const bf16x8*)&Vts[(ne * 16 + col) * 64 + kk * 32 + quad * 8];
        acc_o[ne] = __builtin_amdgcn_mfma_f32_16x16x32_bf16(pa[kk], vb, acc_o[ne], 0, 0, 0);
      }
    }
    __syncthreads();
  }

  float inv[4];
#pragma unroll
  for (int r = 0; r < 4; r++) inv[r] = 1.0f / fmaxf(l_run[r], 1e-20f);
#pragma unroll
  for (int ne = 0; ne < 4; ne++)
#pragma unroll
    for (int r = 0; r < 4; r++) {
      float o = acc_o[ne][r] * inv[r];
      O[((size_t)(b * 512 + i0 + w * 16 + quad * 4 + r)) * 512 + h * 64 + ne * 16 + col] = f2b(o);
    }
}

// Both MLP heads for one sample per block; output dtype per flag.
__global__ __launch_bounds__(256) void heads_kernel(
    const u16* __restrict__ feat,
    const u16* __restrict__ a1w, const u16* __restrict__ a1b,
    const u16* __restrict__ a2w, const u16* __restrict__ a2b,
    const u16* __restrict__ a3w, const u16* __restrict__ a3b,
    const u16* __restrict__ a4w, const u16* __restrict__ a4b,
    const u16* __restrict__ c1w, const u16* __restrict__ c1b,
    const u16* __restrict__ c2w, const u16* __restrict__ c2b,
    const u16* __restrict__ c3w, const u16* __restrict__ c3b,
    const u16* __restrict__ c4w, const u16* __restrict__ c4b,
    const int* __restrict__ flag, void* __restrict__ outv)
{
  __shared__ float f[512];
  __shared__ float g1[256];
  __shared__ float g2[512];
  __shared__ float g3[128];
  int b = blockIdx.x, t = threadIdx.x;
  f[t] = b2f(feat[b * 512 + t]);
  f[t + 256] = b2f(feat[b * 512 + 256 + t]);
  __syncthreads();
  {
    const u16* wrow; float bias;
    if (t < 128) { wrow = a1w + (size_t)t * 512; bias = b2f(a1b[t]); }
    else { wrow = c1w + (size_t)(t - 128) * 512; bias = b2f(c1b[t - 128]); }
    float s = bias;
    for (int k = 0; k < 512; k++) s += b2f(wrow[k]) * f[k];
    g1[t] = gelu_f(s);
  }
  __syncthreads();
  {
    float s1 = b2f(a2b[t]);
    for (int k = 0; k < 128; k++) s1 += b2f(a2w[t * 128 + k]) * g1[k];
    float s2 = b2f(c2b[t]);
    for (int k = 0; k < 128; k++) s2 += b2f(c2w[t * 128 + k]) * g1[128 + k];
    g2[t] = gelu_f(s1);
    g2[256 + t] = gelu_f(s2);
  }
  __syncthreads();
  if (t < 57) {
    float s = b2f(a3b[t]);
    for (int k = 0; k < 256; k++) s += b2f(a3w[t * 256 + k]) * g2[k];
    g3[t] = gelu_f(s);
  } else if (t >= 64 && t < 121) {
    int u = t - 64;
    float s = b2f(c3b[u]);
    for (int k = 0; k < 256; k++) s += b2f(c3w[u * 256 + k]) * g2[256 + k];
    g3[64 + u] = gelu_f(s);
  }
  __syncthreads();
  int fp32out = *flag;
  if (t < 3) {
    float s = b2f(a4b[t]);
    for (int k = 0; k < 57; k++) s += b2f(a4w[t * 57 + k]) * g3[k];
    if (fp32out) ((float*)outv)[b * 3 + t] = s;
    else ((u16*)outv)[b * 3 + t] = f2b(s);
  } else if (t == 4) {
    float s = b2f(c4b[0]);
    for (int k = 0; k < 57; k++) s += b2f(c4w[k]) * g3[64 + k];
    if (fp32out) ((float*)outv)[48 + b] = s;
    else ((u16*)outv)[48 + b] = f2b(s);
  }
}

extern "C" void kernel_launch(void* const* d_in, const int* in_sizes, int n_in,
                              void* d_out, int out_size, void* d_ws, size_t ws_size,
                              hipStream_t stream)
{
  // ws layout: z [0,16M) | R [16M,48M) | bufH [48M,56M) | pool [56M,~85M) | flag @88M
  char* ws = (char*)d_ws;
  float* z    = (float*)ws;
  u16* R      = (u16*)(ws + (16u << 20));
  u16* bufQ   = R;
  u16* bufK   = (u16*)(ws + (24u << 20));
  u16* bufV   = (u16*)(ws + (32u << 20));
  u16* bufVT  = (u16*)(ws + (40u << 20));
  u16* bufO   = bufV;
  u16* bufH   = (u16*)(ws + (48u << 20));
  u16* feat   = R;
  u16* pool   = (u16*)(ws + (56u << 20));
  int* flag   = (int*)(ws + (88u << 20));

  CvtArgs args;
  unsigned int off = 0;
  int nt = n_in < 42 ? n_in : 42;
  for (int i = 0; i < nt; i++) { args.src[i] = d_in[i]; args.off[i] = off; off += (unsigned int)in_sizes[i]; }
  args.off[nt] = off;
  unsigned int total = off;

  probe_kernel<<<1, 64, 0, stream>>>((const unsigned int*)d_in[24], flag);
  cvt_kernel<<<(total + 2047) / 2048, 256, 0, stream>>>(args, nt, total, flag, pool);

  const u16* P[42];
  for (int i = 0; i < nt; i++) P[i] = pool + args.off[i];
  const u16* x       = P[0];
  const u16* conv1_w = P[1];  const u16* conv1_b = P[2];
  const u16* conv2_w = P[3];  const u16* conv2_b = P[4];
  const u16* emb_w   = P[5];  const u16* emb_b   = P[6];
  const u16* pos     = P[7];
  const u16* Wq      = P[8];  const u16* bq      = P[9];
  const u16* Wk      = P[10]; const u16* bk      = P[11];
  const u16* Wv      = P[12]; const u16* bv      = P[13];
  const u16* Wo      = P[14]; const u16* bo      = P[15];
  const u16* ln1_g   = P[16]; const u16* ln1_b   = P[17];
  const u16* ln2_g   = P[18]; const u16* ln2_b   = P[19];
  const u16* W1      = P[20]; const u16* b1      = P[21];
  const u16* W2      = P[22]; const u16* b2      = P[23];
  const u16* lnf_g   = P[24]; const u16* lnf_b   = P[25];

  // conv front-end as im2col + GEMM(+GELU)
  im2col3_kernel<<<dim3(8192, 1), 192, 0, stream>>>(x, R, 64);
  gemm_w64<<<dim3(128, 4, 1), 64, 0, stream>>>(R, conv1_w, conv1_b, bufH, nullptr, 256, 192, 192, 1);
  im2col3_kernel<<<dim3(8192, 3), 256, 0, stream>>>(bufH, R, 256);
  gemm_w64<<<dim3(128, 8, 1), 64, 0, stream>>>(R, conv2_w, conv2_b, bufH, nullptr, 512, 768, 768, 1);
  // residual init: z = pos, then embedding accumulates (split-K x2, atomic)
  zinit_kernel<<<2048, 256, 0, stream>>>(pos, z);
  gemm_w64<<<dim3(128, 8, 2), 64, 0, stream>>>(bufH, emb_w, emb_b, nullptr, z, 512, 512, 256, 3);

  const size_t qkvStride = (8u << 20) / 2;
  for (int l = 0; l < 4; l++) {
    ln_kernel<<<2048, 256, 0, stream>>>(z, ln1_g + l * 512, ln1_b + l * 512, bufH);
    gemm_qkv_w64<<<dim3(128, 24), 64, 0, stream>>>(bufH,
        Wq + (size_t)l * 262144, Wk + (size_t)l * 262144, Wv + (size_t)l * 262144,
        bq + l * 512, bk + l * 512, bv + l * 512, bufQ, qkvStride, 512);
    vtrans_kernel<<<dim3(8, 128), 256, 0, stream>>>(bufV, bufVT);
    attn_kernel<<<dim3(8, 128), 256, 0, stream>>>(bufQ, bufK, bufVT, bufO);
    gemm_w64<<<dim3(128, 8, 2), 64, 0, stream>>>(bufO, Wo + (size_t)l * 262144, bo + l * 512, nullptr, z, 512, 512, 256, 3);
    ln_kernel<<<2048, 256, 0, stream>>>(z, ln2_g + l * 512, ln2_b + l * 512, bufH);
    gemm_w64<<<dim3(128, 32, 1), 64, 0, stream>>>(bufH, W1 + (size_t)l * 1048576, b1 + l * 2048, R, nullptr, 2048, 512, 512, 1);
    gemm_w64<<<dim3(128, 8, 2), 64, 0, stream>>>(R, W2 + (size_t)l * 1048576, b2 + l * 512, nullptr, z, 512, 2048, 1024, 3);
  }

  lnf_kernel<<<4, 256, 0, stream>>>(z, lnf_g, lnf_b, feat);
  heads_kernel<<<16, 256, 0, stream>>>(feat,
      P[26], P[27], P[28], P[29], P[30], P[31], P[32], P[33],
      P[34], P[35], P[36], P[37], P[38], P[39], P[40], P[41],
      flag, d_out);
}

// Round 10
// 1171.580 us; speedup vs baseline: 1.1970x; 1.1970x over previous
//
#include <hip/hip_runtime.h>
#include <hip/hip_bf16.h>
#include <cstdint>

typedef __attribute__((ext_vector_type(8))) short bf16x8;
typedef __attribute__((ext_vector_type(4))) float f32x4;
typedef unsigned short u16;

#define DEV __device__ __forceinline__

DEV float b2f(u16 u) {
  union { unsigned int i; float f; } v; v.i = ((unsigned int)u) << 16; return v.f;
}
DEV u16 f2b(float f) {
  __hip_bfloat16 h = __float2bfloat16(f);
  return *reinterpret_cast<u16*>(&h);
}
DEV float gelu_f(float x) { return 0.5f * x * (1.0f + erff(x * 0.70710678118654752f)); }

DEV void async_cp16(const u16* g, u16* l) {
  __builtin_amdgcn_global_load_lds(
      (const __attribute__((address_space(1))) void*)g,
      (__attribute__((address_space(3))) void*)l, 16, 0, 0);
}

// ---- dtype canonicalization ------------------------------------------------
__global__ void probe_kernel(const unsigned int* __restrict__ g, int* __restrict__ flag) {
  if (threadIdx.x == 0 && blockIdx.x == 0) *flag = (*g == 0x3F800000u) ? 1 : 0;
}

struct CvtArgs {
  const void* src[42];
  unsigned int off[43];
};

struct alignas(16) U8v { u16 u[8]; };

__global__ __launch_bounds__(256) void cvt_kernel(CvtArgs a, int n_t, unsigned int total,
                                                  const int* __restrict__ flag,
                                                  u16* __restrict__ dst) {
  unsigned int i8 = (blockIdx.x * 256u + threadIdx.x) * 8u;
  if (i8 >= total) return;
  int t = 0;
  while (t + 1 < n_t && i8 >= a.off[t + 1]) t++;
  unsigned int j = i8 - a.off[t];
  bool in_seg = (i8 + 8 <= a.off[t + 1]) && (i8 + 8 <= total);
  int fp32 = *flag;
  if (fp32) {
    if (in_seg && ((j & 3) == 0)) {
      const float* s = (const float*)a.src[t] + j;
      float4 v0 = *(const float4*)s;
      float4 v1 = *(const float4*)(s + 4);
      U8v o;
      o.u[0] = f2b(v0.x); o.u[1] = f2b(v0.y); o.u[2] = f2b(v0.z); o.u[3] = f2b(v0.w);
      o.u[4] = f2b(v1.x); o.u[5] = f2b(v1.y); o.u[6] = f2b(v1.z); o.u[7] = f2b(v1.w);
      *(U8v*)(dst + i8) = o;
    } else {
      for (int k = 0; k < 8; k++) {
        unsigned int i = i8 + k;
        if (i >= total) break;
        int tt = t;
        while (tt + 1 < n_t && i >= a.off[tt + 1]) tt++;
        dst[i] = f2b(((const float*)a.src[tt])[i - a.off[tt]]);
      }
    }
  } else {
    if (in_seg && ((j & 7) == 0)) {
      *(U8v*)(dst + i8) = *(const U8v*)((const u16*)a.src[t] + j);
    } else {
      for (int k = 0; k < 8; k++) {
        unsigned int i = i8 + k;
        if (i >= total) break;
        int tt = t;
        while (tt + 1 < n_t && i >= a.off[tt + 1]) tt++;
        dst[i] = ((const u16*)a.src[tt])[i - a.off[tt]];
      }
    }
  }
}

// ---- block-cooperative 128x128 GEMM (m97 structure) + XOR swizzle + split-K -
// mode 1: bf16 out = gelu(x + bias)
// mode 3: f32 atomicAdd(out, x + bias); bias only from blockIdx.z==0
__global__ __launch_bounds__(256) void gemm_bt(
    const u16* __restrict__ A, const u16* __restrict__ W,
    const u16* __restrict__ bias,
    u16* __restrict__ outB, float* __restrict__ outF,
    int N, int K, int kLen, int mode)
{
  __shared__ __align__(16) u16 As[128 * 32];
  __shared__ __align__(16) u16 Bs[128 * 32];
  int t = threadIdx.x, l = t & 63, w = t >> 6;
  int wr = w >> 1, wc = w & 1;
  int col = l & 15, quad = l >> 4;
  int q8 = (quad ^ ((col >> 1) & 3)) * 8;   // read-side swizzle
  int m0 = blockIdx.x * 128;
  int n0 = blockIdx.y * 128;
  int k0 = blockIdx.z * kLen;

  f32x4 acc[4][4];
#pragma unroll
  for (int i = 0; i < 4; i++)
#pragma unroll
    for (int j = 0; j < 4; j++) acc[i][j] = (f32x4){0.f, 0.f, 0.f, 0.f};

  int g1i = t, g2i = t + 256;
  int r1 = g1i >> 2, r2 = g2i >> 2;
  int cb1 = (g1i & 3) ^ ((r1 >> 1) & 3);    // store-side swizzle
  int cb2 = (g2i & 3) ^ ((r2 >> 1) & 3);
  const u16* a1 = A + (size_t)(m0 + r1) * K + k0 + cb1 * 8;
  const u16* a2 = A + (size_t)(m0 + r2) * K + k0 + cb2 * 8;
  const u16* b1 = W + (size_t)(n0 + r1) * K + k0 + cb1 * 8;
  const u16* b2 = W + (size_t)(n0 + r2) * K + k0 + cb2 * 8;
  u16* la1 = &As[g1i * 8];
  u16* la2 = &As[g2i * 8];
  u16* lb1 = &Bs[g1i * 8];
  u16* lb2 = &Bs[g2i * 8];

  for (int kt = 0; kt < kLen; kt += 32) {
    async_cp16(a1 + kt, la1);
    async_cp16(a2 + kt, la2);
    async_cp16(b1 + kt, lb1);
    async_cp16(b2 + kt, lb2);
    __syncthreads();
    bf16x8 af[4], bfv[4];
#pragma unroll
    for (int mi = 0; mi < 4; mi++)
      af[mi] = *(const bf16x8*)&As[(wr * 64 + mi * 16 + col) * 32 + q8];
#pragma unroll
    for (int ni = 0; ni < 4; ni++)
      bfv[ni] = *(const bf16x8*)&Bs[(wc * 64 + ni * 16 + col) * 32 + q8];
#pragma unroll
    for (int mi = 0; mi < 4; mi++)
#pragma unroll
      for (int ni = 0; ni < 4; ni++)
        acc[mi][ni] = __builtin_amdgcn_mfma_f32_16x16x32_bf16(af[mi], bfv[ni], acc[mi][ni], 0, 0, 0);
    __syncthreads();
  }

  int mBase = m0 + wr * 64, nBase = n0 + wc * 64;
  bool addBias = (mode != 3) || (blockIdx.z == 0);
#pragma unroll
  for (int mi = 0; mi < 4; mi++) {
#pragma unroll
    for (int ni = 0; ni < 4; ni++) {
      int n = nBase + ni * 16 + col;
      float bv = addBias ? b2f(bias[n]) : 0.0f;
      f32x4 v = acc[mi][ni];
#pragma unroll
      for (int r = 0; r < 4; r++) {
        int m = mBase + mi * 16 + quad * 4 + r;
        float x = v[r] + bv;
        if (mode == 1) {
          outB[(size_t)m * N + n] = f2b(gelu_f(x));
        } else {
          atomicAdd(&outF[(size_t)m * N + n], x);
        }
      }
    }
  }
}

// Fused Q,K,V projection (same structure, N=1536 logical). y in [0,12).
__global__ __launch_bounds__(256) void gemm_qkv(
    const u16* __restrict__ A,
    const u16* __restrict__ Wq, const u16* __restrict__ Wk, const u16* __restrict__ Wv,
    const u16* __restrict__ bq, const u16* __restrict__ bk, const u16* __restrict__ bv,
    u16* __restrict__ outBase, size_t outStride, int K)
{
  __shared__ __align__(16) u16 As[128 * 32];
  __shared__ __align__(16) u16 Bs[128 * 32];
  int t = threadIdx.x, l = t & 63, w = t >> 6;
  int wr = w >> 1, wc = w & 1;
  int col = l & 15, quad = l >> 4;
  int q8 = (quad ^ ((col >> 1) & 3)) * 8;
  int m0 = blockIdx.x * 128;
  int sel = blockIdx.y >> 2;
  int n0 = (blockIdx.y & 3) * 128;
  const u16* W = sel == 0 ? Wq : (sel == 1 ? Wk : Wv);
  const u16* bias = sel == 0 ? bq : (sel == 1 ? bk : bv);
  u16* outB = outBase + (size_t)sel * outStride;

  f32x4 acc[4][4];
#pragma unroll
  for (int i = 0; i < 4; i++)
#pragma unroll
    for (int j = 0; j < 4; j++) acc[i][j] = (f32x4){0.f, 0.f, 0.f, 0.f};

  int g1i = t, g2i = t + 256;
  int r1 = g1i >> 2, r2 = g2i >> 2;
  int cb1 = (g1i & 3) ^ ((r1 >> 1) & 3);
  int cb2 = (g2i & 3) ^ ((r2 >> 1) & 3);
  const u16* a1 = A + (size_t)(m0 + r1) * K + cb1 * 8;
  const u16* a2 = A + (size_t)(m0 + r2) * K + cb2 * 8;
  const u16* b1 = W + (size_t)(n0 + r1) * K + cb1 * 8;
  const u16* b2 = W + (size_t)(n0 + r2) * K + cb2 * 8;
  u16* la1 = &As[g1i * 8];
  u16* la2 = &As[g2i * 8];
  u16* lb1 = &Bs[g1i * 8];
  u16* lb2 = &Bs[g2i * 8];

  for (int kt = 0; kt < K; kt += 32) {
    async_cp16(a1 + kt, la1);
    async_cp16(a2 + kt, la2);
    async_cp16(b1 + kt, lb1);
    async_cp16(b2 + kt, lb2);
    __syncthreads();
    bf16x8 af[4], bfv[4];
#pragma unroll
    for (int mi = 0; mi < 4; mi++)
      af[mi] = *(const bf16x8*)&As[(wr * 64 + mi * 16 + col) * 32 + q8];
#pragma unroll
    for (int ni = 0; ni < 4; ni++)
      bfv[ni] = *(const bf16x8*)&Bs[(wc * 64 + ni * 16 + col) * 32 + q8];
#pragma unroll
    for (int mi = 0; mi < 4; mi++)
#pragma unroll
      for (int ni = 0; ni < 4; ni++)
        acc[mi][ni] = __builtin_amdgcn_mfma_f32_16x16x32_bf16(af[mi], bfv[ni], acc[mi][ni], 0, 0, 0);
    __syncthreads();
  }

  int mBase = m0 + wr * 64, nBase = n0 + wc * 64;
#pragma unroll
  for (int mi = 0; mi < 4; mi++) {
#pragma unroll
    for (int ni = 0; ni < 4; ni++) {
      int n = nBase + ni * 16 + col;
      float bv = b2f(bias[n]);
      f32x4 v = acc[mi][ni];
#pragma unroll
      for (int r = 0; r < 4; r++) {
        int m = mBase + mi * 16 + quad * 4 + r;
        outB[(size_t)m * 512 + n] = f2b(v[r] + bv);
      }
    }
  }
}

// z[m][n] = pos[(m&511)*512+n]  (fp32 residual init)
__global__ __launch_bounds__(256) void zinit_kernel(const u16* __restrict__ pos,
                                                    float* __restrict__ z)
{
  int i = (blockIdx.x * 256 + threadIdx.x) * 8;
  int n = i & 511;
  int m = i >> 9;
  int s = m & 511;
  U8v p = *(const U8v*)&pos[s * 512 + n];
  float4 o0 = {b2f(p.u[0]), b2f(p.u[1]), b2f(p.u[2]), b2f(p.u[3])};
  float4 o1 = {b2f(p.u[4]), b2f(p.u[5]), b2f(p.u[6]), b2f(p.u[7])};
  *(float4*)(z + i) = o0;
  *(float4*)(z + i + 4) = o1;
}

// dst[m][ci*3+tap] = src[m+tap-1][ci] (zero-padded along s within each batch)
__global__ void im2col3_kernel(const u16* __restrict__ src,
                               u16* __restrict__ dst, int C)
{
  int m = blockIdx.x;
  int k = blockIdx.y * blockDim.x + threadIdx.x;
  int ci = k / 3;
  int tap = k - ci * 3;
  int s = m & 511;
  int sp = s + tap - 1;
  u16 val = 0;
  if (sp >= 0 && sp < 512) val = src[(size_t)(m + tap - 1) * C + ci];
  dst[(size_t)m * (3 * C) + k] = val;
}

// LayerNorm over D=512; one wave per row; z fp32 -> bf16 out.
__global__ __launch_bounds__(256) void ln_kernel(
    const float* __restrict__ z, const u16* __restrict__ gam,
    const u16* __restrict__ bet, u16* __restrict__ out)
{
  int w = threadIdx.x >> 6, l = threadIdx.x & 63;
  int row = blockIdx.x * 4 + w;
  const float* zr = z + (size_t)row * 512;
  float4 v0 = *(const float4*)(zr + l * 8);
  float4 v1 = *(const float4*)(zr + l * 8 + 4);
  float x[8] = {v0.x, v0.y, v0.z, v0.w, v1.x, v1.y, v1.z, v1.w};
  float s = 0.f;
#pragma unroll
  for (int i = 0; i < 8; i++) s += x[i];
#pragma unroll
  for (int mm = 1; mm < 64; mm <<= 1) s += __shfl_xor(s, mm, 64);
  float mu = s * (1.0f / 512.0f);
  float vs = 0.f;
#pragma unroll
  for (int i = 0; i < 8; i++) { float d = x[i] - mu; vs += d * d; }
#pragma unroll
  for (int mm = 1; mm < 64; mm <<= 1) vs += __shfl_xor(vs, mm, 64);
  float rs = rsqrtf(vs * (1.0f / 512.0f) + 1e-5f);
  U8v gg = *(const U8v*)(gam + l * 8);
  U8v bb = *(const U8v*)(bet + l * 8);
  U8v o;
#pragma unroll
  for (int i = 0; i < 8; i++) o.u[i] = f2b((x[i] - mu) * rs * b2f(gg.u[i]) + b2f(bb.u[i]));
  *(U8v*)(out + (size_t)row * 512 + l * 8) = o;
}

// Final LN on last token only: 16 rows (b, s=511) -> feat[b][512]
__global__ __launch_bounds__(256) void lnf_kernel(
    const float* __restrict__ z, const u16* __restrict__ gam,
    const u16* __restrict__ bet, u16* __restrict__ feat)
{
  int w = threadIdx.x >> 6, l = threadIdx.x & 63;
  int b = blockIdx.x * 4 + w;
  const float* zr = z + ((size_t)b * 512 + 511) * 512;
  float4 v0 = *(const float4*)(zr + l * 8);
  float4 v1 = *(const float4*)(zr + l * 8 + 4);
  float x[8] = {v0.x, v0.y, v0.z, v0.w, v1.x, v1.y, v1.z, v1.w};
  float s = 0.f;
#pragma unroll
  for (int i = 0; i < 8; i++) s += x[i];
#pragma unroll
  for (int mm = 1; mm < 64; mm <<= 1) s += __shfl_xor(s, mm, 64);
  float mu = s * (1.0f / 512.0f);
  float vs = 0.f;
#pragma unroll
  for (int i = 0; i < 8; i++) { float d = x[i] - mu; vs += d * d; }
#pragma unroll
  for (int mm = 1; mm < 64; mm <<= 1) vs += __shfl_xor(vs, mm, 64);
  float rs = rsqrtf(vs * (1.0f / 512.0f) + 1e-5f);
  U8v gg = *(const U8v*)(gam + l * 8);
  U8v bb = *(const U8v*)(bet + l * 8);
  U8v o;
#pragma unroll
  for (int i = 0; i < 8; i++) o.u[i] = f2b((x[i] - mu) * rs * b2f(gg.u[i]) + b2f(bb.u[i]));
  *(U8v*)(feat + (size_t)b * 512 + l * 8) = o;
}

// V (b,s,h*64+e) -> VT (b,h,e,s)
__global__ __launch_bounds__(256) void vtrans_kernel(const u16* __restrict__ V,
                                                     u16* __restrict__ VT)
{
  __shared__ u16 tile[64][72];
  int s0 = blockIdx.x * 64;
  int bh = blockIdx.y; int b = bh >> 3, h = bh & 7;
  int t = threadIdx.x;
  int rs = t >> 2, c = (t & 3) * 16;
  const u16* src = V + ((size_t)(b * 512 + s0 + rs) * 512 + h * 64 + c);
  *(float4*)&tile[rs][c] = *(const float4*)src;
  *(float4*)&tile[rs][c + 8] = *(const float4*)(src + 8);
  __syncthreads();
  u16* dst = VT + ((size_t)(bh * 64 + rs) * 512 + s0 + c);
  union { u16 u[16]; float4 f[2]; } ot;
#pragma unroll
  for (int i = 0; i < 16; i++) ot.u[i] = tile[c + i][rs];
  *(float4*)dst = ot.f[0];
  *(float4*)(dst + 8) = ot.f[1];
}

// Fused masked attention, flash-style. LDS rows padded to 72 u16 (144 B)
// to kill the 16-way bank conflicts of the 128 B stride (9.3M cyc in r9).
#define AST 72
__global__ __launch_bounds__(256) void attn_kernel(
    const u16* __restrict__ Q, const u16* __restrict__ Kg,
    const u16* __restrict__ VT, u16* __restrict__ O)
{
  __shared__ __align__(16) u16 Qs[64 * AST];
  __shared__ __align__(16) u16 Ks[64 * AST];
  __shared__ __align__(16) u16 Vts[64 * AST];
  __shared__ __align__(16) u16 Ps[64 * AST];
  const float NEG = -1e30f;
  int bh = blockIdx.y; int b = bh >> 3, h = bh & 7;
  int i0 = blockIdx.x * 64;
  int t = threadIdx.x, w = t >> 6, l = t & 63;
  int col = l & 15, quad = l >> 4;
  int dil = 1 << (h < 4 ? h : 4);
  int per_m1 = 2 * dil - 1;

  {
    int row = t >> 2, c = (t & 3) * 16;
    const u16* src = Q + ((size_t)(b * 512 + i0 + row) * 512 + h * 64 + c);
    *(float4*)&Qs[row * AST + c] = *(const float4*)src;
    *(float4*)&Qs[row * AST + c + 8] = *(const float4*)(src + 8);
  }
  __syncthreads();

  bf16x8 qa[2];
#pragma unroll
  for (int kk = 0; kk < 2; kk++)
    qa[kk] = *(const bf16x8*)&Qs[(w * 16 + col) * AST + kk * 32 + quad * 8];

  f32x4 acc_o[4];
#pragma unroll
  for (int i = 0; i < 4; i++) acc_o[i] = (f32x4){0.f, 0.f, 0.f, 0.f};
  float m_run[4], l_run[4];
#pragma unroll
  for (int r = 0; r < 4; r++) { m_run[r] = NEG; l_run[r] = 0.f; }

  for (int jt = 0; jt < 8; jt++) {
    int j0 = jt * 64;
    {
      int row = t >> 2, c = (t & 3) * 16;
      const u16* ks = Kg + ((size_t)(b * 512 + j0 + row) * 512 + h * 64 + c);
      *(float4*)&Ks[row * AST + c] = *(const float4*)ks;
      *(float4*)&Ks[row * AST + c + 8] = *(const float4*)(ks + 8);
      const u16* vs = VT + ((size_t)(bh * 64 + row) * 512 + j0 + c);
      *(float4*)&Vts[row * AST + c] = *(const float4*)vs;
      *(float4*)&Vts[row * AST + c + 8] = *(const float4*)(vs + 8);
    }
    __syncthreads();

    f32x4 sa[4];
#pragma unroll
    for (int ni = 0; ni < 4; ni++) {
      f32x4 s = (f32x4){0.f, 0.f, 0.f, 0.f};
#pragma unroll
      for (int kk = 0; kk < 2; kk++) {
        bf16x8 kb = *(const bf16x8*)&Ks[(ni * 16 + col) * AST + kk * 32 + quad * 8];
        s = __builtin_amdgcn_mfma_f32_16x16x32_bf16(qa[kk], kb, s, 0, 0, 0);
      }
      sa[ni] = s;
    }

    float pv[4][4];
    float alpha_r[4];
#pragma unroll
    for (int r = 0; r < 4; r++) {
      int ig = i0 + w * 16 + quad * 4 + r;
      float sv[4]; float mx = NEG;
#pragma unroll
      for (int ni = 0; ni < 4; ni++) {
        int jg = j0 + ni * 16 + col;
        int d = ig - jg; d = d < 0 ? -d : d;
        bool keep = (d <= dil) || ((d & per_m1) == 0);
        float s = keep ? fminf(sa[ni][r] * 0.125f, 80.0f) : NEG;
        sv[ni] = s; mx = fmaxf(mx, s);
      }
#pragma unroll
      for (int mm = 1; mm < 16; mm <<= 1) mx = fmaxf(mx, __shfl_xor(mx, mm, 64));
      float mN = fmaxf(m_run[r], mx);
      float a = __expf(m_run[r] - mN);
      float rsum = 0.f;
#pragma unroll
      for (int ni = 0; ni < 4; ni++) { float p = __expf(sv[ni] - mN); pv[ni][r] = p; rsum += p; }
#pragma unroll
      for (int mm = 1; mm < 16; mm <<= 1) rsum += __shfl_xor(rsum, mm, 64);
      l_run[r] = l_run[r] * a + rsum;
      m_run[r] = mN;
      alpha_r[r] = a;
    }
#pragma unroll
    for (int ne = 0; ne < 4; ne++)
#pragma unroll
      for (int r = 0; r < 4; r++) acc_o[ne][r] *= alpha_r[r];
#pragma unroll
    for (int ni = 0; ni < 4; ni++)
#pragma unroll
      for (int r = 0; r < 4; r++)
        Ps[(w * 16 + quad * 4 + r) * AST + ni * 16 + col] = f2b(pv[ni][r]);
    __syncthreads();

    bf16x8 pa[2];
#pragma unroll
    for (int kk = 0; kk < 2; kk++)
      pa[kk] = *(const bf16x8*)&Ps[(w * 16 + col) * AST + kk * 32 + quad * 8];
#pragma unroll
    for (int ne = 0; ne < 4; ne++) {
#pragma unroll
      for (int kk = 0; kk < 2; kk++) {
        bf16x8 vb = *(const bf16x8*)&Vts[(ne * 16 + col) * AST + kk * 32 + quad * 8];
        acc_o[ne] = __builtin_amdgcn_mfma_f32_16x16x32_bf16(pa[kk], vb, acc_o[ne], 0, 0, 0);
      }
    }
    __syncthreads();
  }

  float inv[4];
#pragma unroll
  for (int r = 0; r < 4; r++) inv[r] = 1.0f / fmaxf(l_run[r], 1e-20f);
#pragma unroll
  for (int ne = 0; ne < 4; ne++)
#pragma unroll
    for (int r = 0; r < 4; r++) {
      float o = acc_o[ne][r] * inv[r];
      O[((size_t)(b * 512 + i0 + w * 16 + quad * 4 + r)) * 512 + h * 64 + ne * 16 + col] = f2b(o);
    }
}

// Both MLP heads for one sample per block; output dtype per flag.
__global__ __launch_bounds__(256) void heads_kernel(
    const u16* __restrict__ feat,
    const u16* __restrict__ a1w, const u16* __restrict__ a1b,
    const u16* __restrict__ a2w, const u16* __restrict__ a2b,
    const u16* __restrict__ a3w, const u16* __restrict__ a3b,
    const u16* __restrict__ a4w, const u16* __restrict__ a4b,
    const u16* __restrict__ c1w, const u16* __restrict__ c1b,
    const u16* __restrict__ c2w, const u16* __restrict__ c2b,
    const u16* __restrict__ c3w, const u16* __restrict__ c3b,
    const u16* __restrict__ c4w, const u16* __restrict__ c4b,
    const int* __restrict__ flag, void* __restrict__ outv)
{
  __shared__ float f[512];
  __shared__ float g1[256];
  __shared__ float g2[512];
  __shared__ float g3[128];
  int b = blockIdx.x, t = threadIdx.x;
  f[t] = b2f(feat[b * 512 + t]);
  f[t + 256] = b2f(feat[b * 512 + 256 + t]);
  __syncthreads();
  {
    const u16* wrow; float bias;
    if (t < 128) { wrow = a1w + (size_t)t * 512; bias = b2f(a1b[t]); }
    else { wrow = c1w + (size_t)(t - 128) * 512; bias = b2f(c1b[t - 128]); }
    float s = bias;
    for (int k = 0; k < 512; k++) s += b2f(wrow[k]) * f[k];
    g1[t] = gelu_f(s);
  }
  __syncthreads();
  {
    float s1 = b2f(a2b[t]);
    for (int k = 0; k < 128; k++) s1 += b2f(a2w[t * 128 + k]) * g1[k];
    float s2 = b2f(c2b[t]);
    for (int k = 0; k < 128; k++) s2 += b2f(c2w[t * 128 + k]) * g1[128 + k];
    g2[t] = gelu_f(s1);
    g2[256 + t] = gelu_f(s2);
  }
  __syncthreads();
  if (t < 57) {
    float s = b2f(a3b[t]);
    for (int k = 0; k < 256; k++) s += b2f(a3w[t * 256 + k]) * g2[k];
    g3[t] = gelu_f(s);
  } else if (t >= 64 && t < 121) {
    int u = t - 64;
    float s = b2f(c3b[u]);
    for (int k = 0; k < 256; k++) s += b2f(c3w[u * 256 + k]) * g2[256 + k];
    g3[64 + u] = gelu_f(s);
  }
  __syncthreads();
  int fp32out = *flag;
  if (t < 3) {
    float s = b2f(a4b[t]);
    for (int k = 0; k < 57; k++) s += b2f(a4w[t * 57 + k]) * g3[k];
    if (fp32out) ((float*)outv)[b * 3 + t] = s;
    else ((u16*)outv)[b * 3 + t] = f2b(s);
  } else if (t == 4) {
    float s = b2f(c4b[0]);
    for (int k = 0; k < 57; k++) s += b2f(c4w[k]) * g3[64 + k];
    if (fp32out) ((float*)outv)[48 + b] = s;
    else ((u16*)outv)[48 + b] = f2b(s);
  }
}

extern "C" void kernel_launch(void* const* d_in, const int* in_sizes, int n_in,
                              void* d_out, int out_size, void* d_ws, size_t ws_size,
                              hipStream_t stream)
{
  // ws layout: z [0,16M) | R [16M,48M) | bufH [48M,56M) | pool [56M,~85M) | flag @88M
  char* ws = (char*)d_ws;
  float* z    = (float*)ws;
  u16* R      = (u16*)(ws + (16u << 20));
  u16* bufQ   = R;
  u16* bufK   = (u16*)(ws + (24u << 20));
  u16* bufV   = (u16*)(ws + (32u << 20));
  u16* bufVT  = (u16*)(ws + (40u << 20));
  u16* bufO   = bufV;
  u16* bufH   = (u16*)(ws + (48u << 20));
  u16* feat   = R;
  u16* pool   = (u16*)(ws + (56u << 20));
  int* flag   = (int*)(ws + (88u << 20));

  CvtArgs args;
  unsigned int off = 0;
  int nt = n_in < 42 ? n_in : 42;
  for (int i = 0; i < nt; i++) { args.src[i] = d_in[i]; args.off[i] = off; off += (unsigned int)in_sizes[i]; }
  args.off[nt] = off;
  unsigned int total = off;

  probe_kernel<<<1, 64, 0, stream>>>((const unsigned int*)d_in[24], flag);
  cvt_kernel<<<(total + 2047) / 2048, 256, 0, stream>>>(args, nt, total, flag, pool);

  const u16* P[42];
  for (int i = 0; i < nt; i++) P[i] = pool + args.off[i];
  const u16* x       = P[0];
  const u16* conv1_w = P[1];  const u16* conv1_b = P[2];
  const u16* conv2_w = P[3];  const u16* conv2_b = P[4];
  const u16* emb_w   = P[5];  const u16* emb_b   = P[6];
  const u16* pos     = P[7];
  const u16* Wq      = P[8];  const u16* bq      = P[9];
  const u16* Wk      = P[10]; const u16* bk      = P[11];
  const u16* Wv      = P[12]; const u16* bv      = P[13];
  const u16* Wo      = P[14]; const u16* bo      = P[15];
  const u16* ln1_g   = P[16]; const u16* ln1_b   = P[17];
  const u16* ln2_g   = P[18]; const u16* ln2_b   = P[19];
  const u16* W1      = P[20]; const u16* b1      = P[21];
  const u16* W2      = P[22]; const u16* b2      = P[23];
  const u16* lnf_g   = P[24]; const u16* lnf_b   = P[25];

  // conv front-end as im2col + GEMM(+GELU)
  im2col3_kernel<<<dim3(8192, 1), 192, 0, stream>>>(x, R, 64);
  gemm_bt<<<dim3(64, 2, 1), 256, 0, stream>>>(R, conv1_w, conv1_b, bufH, nullptr, 256, 192, 192, 1);
  im2col3_kernel<<<dim3(8192, 3), 256, 0, stream>>>(bufH, R, 256);
  gemm_bt<<<dim3(64, 4, 1), 256, 0, stream>>>(R, conv2_w, conv2_b, bufH, nullptr, 512, 768, 768, 1);
  // residual init: z = pos, then embedding accumulates (split-K x2, atomic)
  zinit_kernel<<<2048, 256, 0, stream>>>(pos, z);
  gemm_bt<<<dim3(64, 4, 2), 256, 0, stream>>>(bufH, emb_w, emb_b, nullptr, z, 512, 512, 256, 3);

  const size_t qkvStride = (8u << 20) / 2;
  for (int l = 0; l < 4; l++) {
    ln_kernel<<<2048, 256, 0, stream>>>(z, ln1_g + l * 512, ln1_b + l * 512, bufH);
    gemm_qkv<<<dim3(64, 12), 256, 0, stream>>>(bufH,
        Wq + (size_t)l * 262144, Wk + (size_t)l * 262144, Wv + (size_t)l * 262144,
        bq + l * 512, bk + l * 512, bv + l * 512, bufQ, qkvStride, 512);
    vtrans_kernel<<<dim3(8, 128), 256, 0, stream>>>(bufV, bufVT);
    attn_kernel<<<dim3(8, 128), 256, 0, stream>>>(bufQ, bufK, bufVT, bufO);
    gemm_bt<<<dim3(64, 4, 2), 256, 0, stream>>>(bufO, Wo + (size_t)l * 262144, bo + l * 512, nullptr, z, 512, 512, 256, 3);
    ln_kernel<<<2048, 256, 0, stream>>>(z, ln2_g + l * 512, ln2_b + l * 512, bufH);
    gemm_bt<<<dim3(64, 16, 1), 256, 0, stream>>>(bufH, W1 + (size_t)l * 1048576, b1 + l * 2048, R, nullptr, 2048, 512, 512, 1);
    gemm_bt<<<dim3(64, 4, 2), 256, 0, stream>>>(R, W2 + (size_t)l * 1048576, b2 + l * 512, nullptr, z, 512, 2048, 1024, 3);
  }

  lnf_kernel<<<4, 256, 0, stream>>>(z, lnf_g, lnf_b, feat);
  heads_kernel<<<16, 256, 0, stream>>>(feat,
      P[26], P[27], P[28], P[29], P[30], P[31], P[32], P[33],
      P[34], P[35], P[36], P[37], P[38], P[39], P[40], P[41],
      flag, d_out);
}

// Round 11
// 1137.059 us; speedup vs baseline: 1.2333x; 1.0304x over previous
//
#include <hip/hip_runtime.h>
#include <hip/hip_bf16.h>
#include <cstdint>

typedef __attribute__((ext_vector_type(8))) short bf16x8;
typedef __attribute__((ext_vector_type(4))) float f32x4;
typedef unsigned short u16;

#define DEV __device__ __forceinline__

DEV float b2f(u16 u) {
  union { unsigned int i; float f; } v; v.i = ((unsigned int)u) << 16; return v.f;
}
DEV u16 f2b(float f) {
  __hip_bfloat16 h = __float2bfloat16(f);
  return *reinterpret_cast<u16*>(&h);
}
DEV float gelu_f(float x) { return 0.5f * x * (1.0f + erff(x * 0.70710678118654752f)); }

DEV void async_cp16(const u16* g, u16* l) {
  __builtin_amdgcn_global_load_lds(
      (const __attribute__((address_space(1))) void*)g,
      (__attribute__((address_space(3))) void*)l, 16, 0, 0);
}

// ---- dtype canonicalization ------------------------------------------------
__global__ void probe_kernel(const unsigned int* __restrict__ g, int* __restrict__ flag) {
  if (threadIdx.x == 0 && blockIdx.x == 0) *flag = (*g == 0x3F800000u) ? 1 : 0;
}

struct CvtArgs {
  const void* src[42];
  unsigned int off[43];
};

struct alignas(16) U8v { u16 u[8]; };

__global__ __launch_bounds__(256) void cvt_kernel(CvtArgs a, int n_t, unsigned int total,
                                                  const int* __restrict__ flag,
                                                  u16* __restrict__ dst) {
  unsigned int i8 = (blockIdx.x * 256u + threadIdx.x) * 8u;
  if (i8 >= total) return;
  int t = 0;
  while (t + 1 < n_t && i8 >= a.off[t + 1]) t++;
  unsigned int j = i8 - a.off[t];
  bool in_seg = (i8 + 8 <= a.off[t + 1]) && (i8 + 8 <= total);
  int fp32 = *flag;
  if (fp32) {
    if (in_seg && ((j & 3) == 0)) {
      const float* s = (const float*)a.src[t] + j;
      float4 v0 = *(const float4*)s;
      float4 v1 = *(const float4*)(s + 4);
      U8v o;
      o.u[0] = f2b(v0.x); o.u[1] = f2b(v0.y); o.u[2] = f2b(v0.z); o.u[3] = f2b(v0.w);
      o.u[4] = f2b(v1.x); o.u[5] = f2b(v1.y); o.u[6] = f2b(v1.z); o.u[7] = f2b(v1.w);
      *(U8v*)(dst + i8) = o;
    } else {
      for (int k = 0; k < 8; k++) {
        unsigned int i = i8 + k;
        if (i >= total) break;
        int tt = t;
        while (tt + 1 < n_t && i >= a.off[tt + 1]) tt++;
        dst[i] = f2b(((const float*)a.src[tt])[i - a.off[tt]]);
      }
    }
  } else {
    if (in_seg && ((j & 7) == 0)) {
      *(U8v*)(dst + i8) = *(const U8v*)((const u16*)a.src[t] + j);
    } else {
      for (int k = 0; k < 8; k++) {
        unsigned int i = i8 + k;
        if (i >= total) break;
        int tt = t;
        while (tt + 1 < n_t && i >= a.off[tt + 1]) tt++;
        dst[i] = ((const u16*)a.src[tt])[i - a.off[tt]];
      }
    }
  }
}

// ---- 128x128 GEMM, double-buffered LDS, raw barriers + vmcnt(4) -------------
// Stage tile k+1 while computing tile k; the vmcnt wait covers loads issued a
// full iteration earlier, so L2/HBM latency is hidden behind the 16 MFMAs.
// XOR swizzle (r10-verified: conflicts 0) retained.
// mode 1: bf16 out = gelu(x + bias)
// mode 3: f32 atomicAdd(out, x + bias); bias only from blockIdx.z==0
__global__ __launch_bounds__(256) void gemm_bt(
    const u16* __restrict__ A, const u16* __restrict__ W,
    const u16* __restrict__ bias,
    u16* __restrict__ outB, float* __restrict__ outF,
    int N, int K, int kLen, int mode)
{
  __shared__ __align__(16) u16 As[2][128 * 32];
  __shared__ __align__(16) u16 Bs[2][128 * 32];
  int t = threadIdx.x, l = t & 63, w = t >> 6;
  int wr = w >> 1, wc = w & 1;
  int col = l & 15, quad = l >> 4;
  int q8 = (quad ^ ((col >> 1) & 3)) * 8;
  int m0 = blockIdx.x * 128;
  int n0 = blockIdx.y * 128;
  int k0 = blockIdx.z * kLen;

  f32x4 acc[4][4];
#pragma unroll
  for (int i = 0; i < 4; i++)
#pragma unroll
    for (int j = 0; j < 4; j++) acc[i][j] = (f32x4){0.f, 0.f, 0.f, 0.f};

  int g1i = t, g2i = t + 256;
  int r1 = g1i >> 2, r2 = g2i >> 2;
  int cb1 = (g1i & 3) ^ ((r1 >> 1) & 3);
  int cb2 = (g2i & 3) ^ ((r2 >> 1) & 3);
  const u16* a1 = A + (size_t)(m0 + r1) * K + k0 + cb1 * 8;
  const u16* a2 = A + (size_t)(m0 + r2) * K + k0 + cb2 * 8;
  const u16* b1 = W + (size_t)(n0 + r1) * K + k0 + cb1 * 8;
  const u16* b2 = W + (size_t)(n0 + r2) * K + k0 + cb2 * 8;

  int nK = kLen >> 5;
  // prologue: stage tile 0 into buffer 0
  async_cp16(a1, &As[0][g1i * 8]);
  async_cp16(a2, &As[0][g2i * 8]);
  async_cp16(b1, &Bs[0][g1i * 8]);
  async_cp16(b2, &Bs[0][g2i * 8]);
  for (int ki = 0; ki < nK; ki++) {
    int cur = ki & 1;
    if (ki + 1 < nK) {
      int nxt = cur ^ 1, kt = (ki + 1) << 5;
      async_cp16(a1 + kt, &As[nxt][g1i * 8]);
      async_cp16(a2 + kt, &As[nxt][g2i * 8]);
      async_cp16(b1 + kt, &Bs[nxt][g1i * 8]);
      async_cp16(b2 + kt, &Bs[nxt][g2i * 8]);
      __builtin_amdgcn_s_waitcnt(0x0F74);  // vmcnt(4): tile ki landed
    } else {
      __builtin_amdgcn_s_waitcnt(0x0F70);  // vmcnt(0)
    }
    __builtin_amdgcn_s_barrier();          // all waves' tile-ki loads visible
    __builtin_amdgcn_sched_barrier(0);
    bf16x8 af[4], bfv[4];
#pragma unroll
    for (int mi = 0; mi < 4; mi++)
      af[mi] = *(const bf16x8*)&As[cur][(wr * 64 + mi * 16 + col) * 32 + q8];
#pragma unroll
    for (int ni = 0; ni < 4; ni++)
      bfv[ni] = *(const bf16x8*)&Bs[cur][(wc * 64 + ni * 16 + col) * 32 + q8];
#pragma unroll
    for (int mi = 0; mi < 4; mi++)
#pragma unroll
      for (int ni = 0; ni < 4; ni++)
        acc[mi][ni] = __builtin_amdgcn_mfma_f32_16x16x32_bf16(af[mi], bfv[ni], acc[mi][ni], 0, 0, 0);
    __builtin_amdgcn_sched_barrier(0);
    __builtin_amdgcn_s_barrier();          // cur fully read before overwrite
  }

  int mBase = m0 + wr * 64, nBase = n0 + wc * 64;
  bool addBias = (mode != 3) || (blockIdx.z == 0);
#pragma unroll
  for (int mi = 0; mi < 4; mi++) {
#pragma unroll
    for (int ni = 0; ni < 4; ni++) {
      int n = nBase + ni * 16 + col;
      float bv = addBias ? b2f(bias[n]) : 0.0f;
      f32x4 v = acc[mi][ni];
#pragma unroll
      for (int r = 0; r < 4; r++) {
        int m = mBase + mi * 16 + quad * 4 + r;
        float x = v[r] + bv;
        if (mode == 1) {
          outB[(size_t)m * N + n] = f2b(gelu_f(x));
        } else {
          atomicAdd(&outF[(size_t)m * N + n], x);
        }
      }
    }
  }
}

// Fused Q,K,V projection (same dbuf structure). y in [0,12).
__global__ __launch_bounds__(256) void gemm_qkv(
    const u16* __restrict__ A,
    const u16* __restrict__ Wq, const u16* __restrict__ Wk, const u16* __restrict__ Wv,
    const u16* __restrict__ bq, const u16* __restrict__ bk, const u16* __restrict__ bv,
    u16* __restrict__ outBase, size_t outStride, int K)
{
  __shared__ __align__(16) u16 As[2][128 * 32];
  __shared__ __align__(16) u16 Bs[2][128 * 32];
  int t = threadIdx.x, l = t & 63, w = t >> 6;
  int wr = w >> 1, wc = w & 1;
  int col = l & 15, quad = l >> 4;
  int q8 = (quad ^ ((col >> 1) & 3)) * 8;
  int m0 = blockIdx.x * 128;
  int sel = blockIdx.y >> 2;
  int n0 = (blockIdx.y & 3) * 128;
  const u16* W = sel == 0 ? Wq : (sel == 1 ? Wk : Wv);
  const u16* bias = sel == 0 ? bq : (sel == 1 ? bk : bv);
  u16* outB = outBase + (size_t)sel * outStride;

  f32x4 acc[4][4];
#pragma unroll
  for (int i = 0; i < 4; i++)
#pragma unroll
    for (int j = 0; j < 4; j++) acc[i][j] = (f32x4){0.f, 0.f, 0.f, 0.f};

  int g1i = t, g2i = t + 256;
  int r1 = g1i >> 2, r2 = g2i >> 2;
  int cb1 = (g1i & 3) ^ ((r1 >> 1) & 3);
  int cb2 = (g2i & 3) ^ ((r2 >> 1) & 3);
  const u16* a1 = A + (size_t)(m0 + r1) * K + cb1 * 8;
  const u16* a2 = A + (size_t)(m0 + r2) * K + cb2 * 8;
  const u16* b1 = W + (size_t)(n0 + r1) * K + cb1 * 8;
  const u16* b2 = W + (size_t)(n0 + r2) * K + cb2 * 8;

  int nK = K >> 5;
  async_cp16(a1, &As[0][g1i * 8]);
  async_cp16(a2, &As[0][g2i * 8]);
  async_cp16(b1, &Bs[0][g1i * 8]);
  async_cp16(b2, &Bs[0][g2i * 8]);
  for (int ki = 0; ki < nK; ki++) {
    int cur = ki & 1;
    if (ki + 1 < nK) {
      int nxt = cur ^ 1, kt = (ki + 1) << 5;
      async_cp16(a1 + kt, &As[nxt][g1i * 8]);
      async_cp16(a2 + kt, &As[nxt][g2i * 8]);
      async_cp16(b1 + kt, &Bs[nxt][g1i * 8]);
      async_cp16(b2 + kt, &Bs[nxt][g2i * 8]);
      __builtin_amdgcn_s_waitcnt(0x0F74);
    } else {
      __builtin_amdgcn_s_waitcnt(0x0F70);
    }
    __builtin_amdgcn_s_barrier();
    __builtin_amdgcn_sched_barrier(0);
    bf16x8 af[4], bfv[4];
#pragma unroll
    for (int mi = 0; mi < 4; mi++)
      af[mi] = *(const bf16x8*)&As[cur][(wr * 64 + mi * 16 + col) * 32 + q8];
#pragma unroll
    for (int ni = 0; ni < 4; ni++)
      bfv[ni] = *(const bf16x8*)&Bs[cur][(wc * 64 + ni * 16 + col) * 32 + q8];
#pragma unroll
    for (int mi = 0; mi < 4; mi++)
#pragma unroll
      for (int ni = 0; ni < 4; ni++)
        acc[mi][ni] = __builtin_amdgcn_mfma_f32_16x16x32_bf16(af[mi], bfv[ni], acc[mi][ni], 0, 0, 0);
    __builtin_amdgcn_sched_barrier(0);
    __builtin_amdgcn_s_barrier();
  }

  int mBase = m0 + wr * 64, nBase = n0 + wc * 64;
#pragma unroll
  for (int mi = 0; mi < 4; mi++) {
#pragma unroll
    for (int ni = 0; ni < 4; ni++) {
      int n = nBase + ni * 16 + col;
      float bv = b2f(bias[n]);
      f32x4 v = acc[mi][ni];
#pragma unroll
      for (int r = 0; r < 4; r++) {
        int m = mBase + mi * 16 + quad * 4 + r;
        outB[(size_t)m * 512 + n] = f2b(v[r] + bv);
      }
    }
  }
}

// z[m][n] = pos[(m&511)*512+n]  (fp32 residual init)
__global__ __launch_bounds__(256) void zinit_kernel(const u16* __restrict__ pos,
                                                    float* __restrict__ z)
{
  int i = (blockIdx.x * 256 + threadIdx.x) * 8;
  int n = i & 511;
  int m = i >> 9;
  int s = m & 511;
  U8v p = *(const U8v*)&pos[s * 512 + n];
  float4 o0 = {b2f(p.u[0]), b2f(p.u[1]), b2f(p.u[2]), b2f(p.u[3])};
  float4 o1 = {b2f(p.u[4]), b2f(p.u[5]), b2f(p.u[6]), b2f(p.u[7])};
  *(float4*)(z + i) = o0;
  *(float4*)(z + i + 4) = o1;
}

// dst[m][ci*3+tap] = src[m+tap-1][ci] (zero-padded along s within each batch)
__global__ void im2col3_kernel(const u16* __restrict__ src,
                               u16* __restrict__ dst, int C)
{
  int m = blockIdx.x;
  int k = blockIdx.y * blockDim.x + threadIdx.x;
  int ci = k / 3;
  int tap = k - ci * 3;
  int s = m & 511;
  int sp = s + tap - 1;
  u16 val = 0;
  if (sp >= 0 && sp < 512) val = src[(size_t)(m + tap - 1) * C + ci];
  dst[(size_t)m * (3 * C) + k] = val;
}

// LayerNorm over D=512; one wave per row; z fp32 -> bf16 out.
__global__ __launch_bounds__(256) void ln_kernel(
    const float* __restrict__ z, const u16* __restrict__ gam,
    const u16* __restrict__ bet, u16* __restrict__ out)
{
  int w = threadIdx.x >> 6, l = threadIdx.x & 63;
  int row = blockIdx.x * 4 + w;
  const float* zr = z + (size_t)row * 512;
  float4 v0 = *(const float4*)(zr + l * 8);
  float4 v1 = *(const float4*)(zr + l * 8 + 4);
  float x[8] = {v0.x, v0.y, v0.z, v0.w, v1.x, v1.y, v1.z, v1.w};
  float s = 0.f;
#pragma unroll
  for (int i = 0; i < 8; i++) s += x[i];
#pragma unroll
  for (int mm = 1; mm < 64; mm <<= 1) s += __shfl_xor(s, mm, 64);
  float mu = s * (1.0f / 512.0f);
  float vs = 0.f;
#pragma unroll
  for (int i = 0; i < 8; i++) { float d = x[i] - mu; vs += d * d; }
#pragma unroll
  for (int mm = 1; mm < 64; mm <<= 1) vs += __shfl_xor(vs, mm, 64);
  float rs = rsqrtf(vs * (1.0f / 512.0f) + 1e-5f);
  U8v gg = *(const U8v*)(gam + l * 8);
  U8v bb = *(const U8v*)(bet + l * 8);
  U8v o;
#pragma unroll
  for (int i = 0; i < 8; i++) o.u[i] = f2b((x[i] - mu) * rs * b2f(gg.u[i]) + b2f(bb.u[i]));
  *(U8v*)(out + (size_t)row * 512 + l * 8) = o;
}

// Final LN on last token only: 16 rows (b, s=511) -> feat[b][512]
__global__ __launch_bounds__(256) void lnf_kernel(
    const float* __restrict__ z, const u16* __restrict__ gam,
    const u16* __restrict__ bet, u16* __restrict__ feat)
{
  int w = threadIdx.x >> 6, l = threadIdx.x & 63;
  int b = blockIdx.x * 4 + w;
  const float* zr = z + ((size_t)b * 512 + 511) * 512;
  float4 v0 = *(const float4*)(zr + l * 8);
  float4 v1 = *(const float4*)(zr + l * 8 + 4);
  float x[8] = {v0.x, v0.y, v0.z, v0.w, v1.x, v1.y, v1.z, v1.w};
  float s = 0.f;
#pragma unroll
  for (int i = 0; i < 8; i++) s += x[i];
#pragma unroll
  for (int mm = 1; mm < 64; mm <<= 1) s += __shfl_xor(s, mm, 64);
  float mu = s * (1.0f / 512.0f);
  float vs = 0.f;
#pragma unroll
  for (int i = 0; i < 8; i++) { float d = x[i] - mu; vs += d * d; }
#pragma unroll
  for (int mm = 1; mm < 64; mm <<= 1) vs += __shfl_xor(vs, mm, 64);
  float rs = rsqrtf(vs * (1.0f / 512.0f) + 1e-5f);
  U8v gg = *(const U8v*)(gam + l * 8);
  U8v bb = *(const U8v*)(bet + l * 8);
  U8v o;
#pragma unroll
  for (int i = 0; i < 8; i++) o.u[i] = f2b((x[i] - mu) * rs * b2f(gg.u[i]) + b2f(bb.u[i]));
  *(U8v*)(feat + (size_t)b * 512 + l * 8) = o;
}

// V (b,s,h*64+e) -> VT (b,h,e,s)
__global__ __launch_bounds__(256) void vtrans_kernel(const u16* __restrict__ V,
                                                     u16* __restrict__ VT)
{
  __shared__ u16 tile[64][72];
  int s0 = blockIdx.x * 64;
  int bh = blockIdx.y; int b = bh >> 3, h = bh & 7;
  int t = threadIdx.x;
  int rs = t >> 2, c = (t & 3) * 16;
  const u16* src = V + ((size_t)(b * 512 + s0 + rs) * 512 + h * 64 + c);
  *(float4*)&tile[rs][c] = *(const float4*)src;
  *(float4*)&tile[rs][c + 8] = *(const float4*)(src + 8);
  __syncthreads();
  u16* dst = VT + ((size_t)(bh * 64 + rs) * 512 + s0 + c);
  union { u16 u[16]; float4 f[2]; } ot;
#pragma unroll
  for (int i = 0; i < 16; i++) ot.u[i] = tile[c + i][rs];
  *(float4*)dst = ot.f[0];
  *(float4*)(dst + 8) = ot.f[1];
}

// Fused masked attention, flash-style. LDS rows padded to 72 u16 (144 B).
#define AST 72
__global__ __launch_bounds__(256) void attn_kernel(
    const u16* __restrict__ Q, const u16* __restrict__ Kg,
    const u16* __restrict__ VT, u16* __restrict__ O)
{
  __shared__ __align__(16) u16 Qs[64 * AST];
  __shared__ __align__(16) u16 Ks[64 * AST];
  __shared__ __align__(16) u16 Vts[64 * AST];
  __shared__ __align__(16) u16 Ps[64 * AST];
  const float NEG = -1e30f;
  int bh = blockIdx.y; int b = bh >> 3, h = bh & 7;
  int i0 = blockIdx.x * 64;
  int t = threadIdx.x, w = t >> 6, l = t & 63;
  int col = l & 15, quad = l >> 4;
  int dil = 1 << (h < 4 ? h : 4);
  int per_m1 = 2 * dil - 1;

  {
    int row = t >> 2, c = (t & 3) * 16;
    const u16* src = Q + ((size_t)(b * 512 + i0 + row) * 512 + h * 64 + c);
    *(float4*)&Qs[row * AST + c] = *(const float4*)src;
    *(float4*)&Qs[row * AST + c + 8] = *(const float4*)(src + 8);
  }
  __syncthreads();

  bf16x8 qa[2];
#pragma unroll
  for (int kk = 0; kk < 2; kk++)
    qa[kk] = *(const bf16x8*)&Qs[(w * 16 + col) * AST + kk * 32 + quad * 8];

  f32x4 acc_o[4];
#pragma unroll
  for (int i = 0; i < 4; i++) acc_o[i] = (f32x4){0.f, 0.f, 0.f, 0.f};
  float m_run[4], l_run[4];
#pragma unroll
  for (int r = 0; r < 4; r++) { m_run[r] = NEG; l_run[r] = 0.f; }

  for (int jt = 0; jt < 8; jt++) {
    int j0 = jt * 64;
    {
      int row = t >> 2, c = (t & 3) * 16;
      const u16* ks = Kg + ((size_t)(b * 512 + j0 + row) * 512 + h * 64 + c);
      *(float4*)&Ks[row * AST + c] = *(const float4*)ks;
      *(float4*)&Ks[row * AST + c + 8] = *(const float4*)(ks + 8);
      const u16* vs = VT + ((size_t)(bh * 64 + row) * 512 + j0 + c);
      *(float4*)&Vts[row * AST + c] = *(const float4*)vs;
      *(float4*)&Vts[row * AST + c + 8] = *(const float4*)(vs + 8);
    }
    __syncthreads();

    f32x4 sa[4];
#pragma unroll
    for (int ni = 0; ni < 4; ni++) {
      f32x4 s = (f32x4){0.f, 0.f, 0.f, 0.f};
#pragma unroll
      for (int kk = 0; kk < 2; kk++) {
        bf16x8 kb = *(const bf16x8*)&Ks[(ni * 16 + col) * AST + kk * 32 + quad * 8];
        s = __builtin_amdgcn_mfma_f32_16x16x32_bf16(qa[kk], kb, s, 0, 0, 0);
      }
      sa[ni] = s;
    }

    float pv[4][4];
    float alpha_r[4];
#pragma unroll
    for (int r = 0; r < 4; r++) {
      int ig = i0 + w * 16 + quad * 4 + r;
      float sv[4]; float mx = NEG;
#pragma unroll
      for (int ni = 0; ni < 4; ni++) {
        int jg = j0 + ni * 16 + col;
        int d = ig - jg; d = d < 0 ? -d : d;
        bool keep = (d <= dil) || ((d & per_m1) == 0);
        float s = keep ? fminf(sa[ni][r] * 0.125f, 80.0f) : NEG;
        sv[ni] = s; mx = fmaxf(mx, s);
      }
#pragma unroll
      for (int mm = 1; mm < 16; mm <<= 1) mx = fmaxf(mx, __shfl_xor(mx, mm, 64));
      float mN = fmaxf(m_run[r], mx);
      float a = __expf(m_run[r] - mN);
      float rsum = 0.f;
#pragma unroll
      for (int ni = 0; ni < 4; ni++) { float p = __expf(sv[ni] - mN); pv[ni][r] = p; rsum += p; }
#pragma unroll
      for (int mm = 1; mm < 16; mm <<= 1) rsum += __shfl_xor(rsum, mm, 64);
      l_run[r] = l_run[r] * a + rsum;
      m_run[r] = mN;
      alpha_r[r] = a;
    }
#pragma unroll
    for (int ne = 0; ne < 4; ne++)
#pragma unroll
      for (int r = 0; r < 4; r++) acc_o[ne][r] *= alpha_r[r];
#pragma unroll
    for (int ni = 0; ni < 4; ni++)
#pragma unroll
      for (int r = 0; r < 4; r++)
        Ps[(w * 16 + quad * 4 + r) * AST + ni * 16 + col] = f2b(pv[ni][r]);
    __syncthreads();

    bf16x8 pa[2];
#pragma unroll
    for (int kk = 0; kk < 2; kk++)
      pa[kk] = *(const bf16x8*)&Ps[(w * 16 + col) * AST + kk * 32 + quad * 8];
#pragma unroll
    for (int ne = 0; ne < 4; ne++) {
#pragma unroll
      for (int kk = 0; kk < 2; kk++) {
        bf16x8 vb = *(const bf16x8*)&Vts[(ne * 16 + col) * AST + kk * 32 + quad * 8];
        acc_o[ne] = __builtin_amdgcn_mfma_f32_16x16x32_bf16(pa[kk], vb, acc_o[ne], 0, 0, 0);
      }
    }
    __syncthreads();
  }

  float inv[4];
#pragma unroll
  for (int r = 0; r < 4; r++) inv[r] = 1.0f / fmaxf(l_run[r], 1e-20f);
#pragma unroll
  for (int ne = 0; ne < 4; ne++)
#pragma unroll
    for (int r = 0; r < 4; r++) {
      float o = acc_o[ne][r] * inv[r];
      O[((size_t)(b * 512 + i0 + w * 16 + quad * 4 + r)) * 512 + h * 64 + ne * 16 + col] = f2b(o);
    }
}

// Both MLP heads for one sample per block; output dtype per flag.
__global__ __launch_bounds__(256) void heads_kernel(
    const u16* __restrict__ feat,
    const u16* __restrict__ a1w, const u16* __restrict__ a1b,
    const u16* __restrict__ a2w, const u16* __restrict__ a2b,
    const u16* __restrict__ a3w, const u16* __restrict__ a3b,
    const u16* __restrict__ a4w, const u16* __restrict__ a4b,
    const u16* __restrict__ c1w, const u16* __restrict__ c1b,
    const u16* __restrict__ c2w, const u16* __restrict__ c2b,
    const u16* __restrict__ c3w, const u16* __restrict__ c3b,
    const u16* __restrict__ c4w, const u16* __restrict__ c4b,
    const int* __restrict__ flag, void* __restrict__ outv)
{
  __shared__ float f[512];
  __shared__ float g1[256];
  __shared__ float g2[512];
  __shared__ float g3[128];
  int b = blockIdx.x, t = threadIdx.x;
  f[t] = b2f(feat[b * 512 + t]);
  f[t + 256] = b2f(feat[b * 512 + 256 + t]);
  __syncthreads();
  {
    const u16* wrow; float bias;
    if (t < 128) { wrow = a1w + (size_t)t * 512; bias = b2f(a1b[t]); }
    else { wrow = c1w + (size_t)(t - 128) * 512; bias = b2f(c1b[t - 128]); }
    float s = bias;
    for (int k = 0; k < 512; k++) s += b2f(wrow[k]) * f[k];
    g1[t] = gelu_f(s);
  }
  __syncthreads();
  {
    float s1 = b2f(a2b[t]);
    for (int k = 0; k < 128; k++) s1 += b2f(a2w[t * 128 + k]) * g1[k];
    float s2 = b2f(c2b[t]);
    for (int k = 0; k < 128; k++) s2 += b2f(c2w[t * 128 + k]) * g1[128 + k];
    g2[t] = gelu_f(s1);
    g2[256 + t] = gelu_f(s2);
  }
  __syncthreads();
  if (t < 57) {
    float s = b2f(a3b[t]);
    for (int k = 0; k < 256; k++) s += b2f(a3w[t * 256 + k]) * g2[k];
    g3[t] = gelu_f(s);
  } else if (t >= 64 && t < 121) {
    int u = t - 64;
    float s = b2f(c3b[u]);
    for (int k = 0; k < 256; k++) s += b2f(c3w[u * 256 + k]) * g2[256 + k];
    g3[64 + u] = gelu_f(s);
  }
  __syncthreads();
  int fp32out = *flag;
  if (t < 3) {
    float s = b2f(a4b[t]);
    for (int k = 0; k < 57; k++) s += b2f(a4w[t * 57 + k]) * g3[k];
    if (fp32out) ((float*)outv)[b * 3 + t] = s;
    else ((u16*)outv)[b * 3 + t] = f2b(s);
  } else if (t == 4) {
    float s = b2f(c4b[0]);
    for (int k = 0; k < 57; k++) s += b2f(c4w[k]) * g3[64 + k];
    if (fp32out) ((float*)outv)[48 + b] = s;
    else ((u16*)outv)[48 + b] = f2b(s);
  }
}

extern "C" void kernel_launch(void* const* d_in, const int* in_sizes, int n_in,
                              void* d_out, int out_size, void* d_ws, size_t ws_size,
                              hipStream_t stream)
{
  // ws layout: z [0,16M) | R [16M,48M) | bufH [48M,56M) | pool [56M,~85M) | flag @88M
  char* ws = (char*)d_ws;
  float* z    = (float*)ws;
  u16* R      = (u16*)(ws + (16u << 20));
  u16* bufQ   = R;
  u16* bufK   = (u16*)(ws + (24u << 20));
  u16* bufV   = (u16*)(ws + (32u << 20));
  u16* bufVT  = (u16*)(ws + (40u << 20));
  u16* bufO   = bufV;
  u16* bufH   = (u16*)(ws + (48u << 20));
  u16* feat   = R;
  u16* pool   = (u16*)(ws + (56u << 20));
  int* flag   = (int*)(ws + (88u << 20));

  CvtArgs args;
  unsigned int off = 0;
  int nt = n_in < 42 ? n_in : 42;
  for (int i = 0; i < nt; i++) { args.src[i] = d_in[i]; args.off[i] = off; off += (unsigned int)in_sizes[i]; }
  args.off[nt] = off;
  unsigned int total = off;

  probe_kernel<<<1, 64, 0, stream>>>((const unsigned int*)d_in[24], flag);
  cvt_kernel<<<(total + 2047) / 2048, 256, 0, stream>>>(args, nt, total, flag, pool);

  const u16* P[42];
  for (int i = 0; i < nt; i++) P[i] = pool + args.off[i];
  const u16* x       = P[0];
  const u16* conv1_w = P[1];  const u16* conv1_b = P[2];
  const u16* conv2_w = P[3];  const u16* conv2_b = P[4];
  const u16* emb_w   = P[5];  const u16* emb_b   = P[6];
  const u16* pos     = P[7];
  const u16* Wq      = P[8];  const u16* bq      = P[9];
  const u16* Wk      = P[10]; const u16* bk      = P[11];
  const u16* Wv      = P[12]; const u16* bv      = P[13];
  const u16* Wo      = P[14]; const u16* bo      = P[15];
  const u16* ln1_g   = P[16]; const u16* ln1_b   = P[17];
  const u16* ln2_g   = P[18]; const u16* ln2_b   = P[19];
  const u16* W1      = P[20]; const u16* b1      = P[21];
  const u16* W2      = P[22]; const u16* b2      = P[23];
  const u16* lnf_g   = P[24]; const u16* lnf_b   = P[25];

  // conv front-end as im2col + GEMM(+GELU)
  im2col3_kernel<<<dim3(8192, 1), 192, 0, stream>>>(x, R, 64);
  gemm_bt<<<dim3(64, 2, 1), 256, 0, stream>>>(R, conv1_w, conv1_b, bufH, nullptr, 256, 192, 192, 1);
  im2col3_kernel<<<dim3(8192, 3), 256, 0, stream>>>(bufH, R, 256);
  gemm_bt<<<dim3(64, 4, 1), 256, 0, stream>>>(R, conv2_w, conv2_b, bufH, nullptr, 512, 768, 768, 1);
  // residual init: z = pos, then embedding accumulates (split-K x2, atomic)
  zinit_kernel<<<2048, 256, 0, stream>>>(pos, z);
  gemm_bt<<<dim3(64, 4, 2), 256, 0, stream>>>(bufH, emb_w, emb_b, nullptr, z, 512, 512, 256, 3);

  const size_t qkvStride = (8u << 20) / 2;
  for (int l = 0; l < 4; l++) {
    ln_kernel<<<2048, 256, 0, stream>>>(z, ln1_g + l * 512, ln1_b + l * 512, bufH);
    gemm_qkv<<<dim3(64, 12), 256, 0, stream>>>(bufH,
        Wq + (size_t)l * 262144, Wk + (size_t)l * 262144, Wv + (size_t)l * 262144,
        bq + l * 512, bk + l * 512, bv + l * 512, bufQ, qkvStride, 512);
    vtrans_kernel<<<dim3(8, 128), 256, 0, stream>>>(bufV, bufVT);
    attn_kernel<<<dim3(8, 128), 256, 0, stream>>>(bufQ, bufK, bufVT, bufO);
    gemm_bt<<<dim3(64, 4, 2), 256, 0, stream>>>(bufO, Wo + (size_t)l * 262144, bo + l * 512, nullptr, z, 512, 512, 256, 3);
    ln_kernel<<<2048, 256, 0, stream>>>(z, ln2_g + l * 512, ln2_b + l * 512, bufH);
    gemm_bt<<<dim3(64, 16, 1), 256, 0, stream>>>(bufH, W1 + (size_t)l * 1048576, b1 + l * 2048, R, nullptr, 2048, 512, 512, 1);
    gemm_bt<<<dim3(64, 4, 2), 256, 0, stream>>>(R, W2 + (size_t)l * 1048576, b2 + l * 512, nullptr, z, 512, 2048, 1024, 3);
  }

  lnf_kernel<<<4, 256, 0, stream>>>(z, lnf_g, lnf_b, feat);
  heads_kernel<<<16, 256, 0, stream>>>(feat,
      P[26], P[27], P[28], P[29], P[30], P[31], P[32], P[33],
      P[34], P[35], P[36], P[37], P[38], P[39], P[40], P[41],
      flag, d_out);
}